// Round 11
// baseline (123.924 us; speedup 1.0000x reference)
//
#include <hip/hip_runtime.h>

#define LN_EPS 1e-5f

typedef _Float16 f16x4 __attribute__((ext_vector_type(4)));
typedef float f32x4 __attribute__((ext_vector_type(4)));
typedef unsigned int u32;
typedef u32 u32x2 __attribute__((ext_vector_type(2)));

#if defined(__HIP_DEVICE_COMPILE__)
#  if __has_builtin(__builtin_amdgcn_mfma_f32_16x16x16f16)
#    define MFMA16(a, b, c) __builtin_amdgcn_mfma_f32_16x16x16f16(a, b, c, 0, 0, 0)
#  elif __has_builtin(__builtin_amdgcn_mfma_f32_16x16x16_f16)
#    define MFMA16(a, b, c) __builtin_amdgcn_mfma_f32_16x16x16_f16(a, b, c, 0, 0, 0)
#  else
#    error "no 16x16x16 f16 mfma builtin on device"
#  endif
#else
#  define MFMA16(a, b, c) (c)   /* host pass: parse-only dummy, never executed */
#endif

__device__ __forceinline__ float fast_rcp(float x) { return __builtin_amdgcn_rcpf(x); }

__device__ __forceinline__ u32 pk2(float a, float b) {
    return __builtin_bit_cast(u32, __builtin_amdgcn_cvt_pkrtz(a, b));
}
__device__ __forceinline__ f16x4 mk4(float a, float b, float c, float d) {
    u32x2 t = {pk2(a, b), pk2(c, d)};
    return __builtin_bit_cast(f16x4, t);
}

// 4-way silu with ONE v_rcp. exp-arg clamp 20: (1+e^20)^4 ~ 5.5e34 < f32max.
// sigma(-20) = 2e-9 -> clamp error negligible.
__device__ __forceinline__ void silu_quad(float a0, float a1, float a2, float a3,
                                          float& s0, float& s1, float& s2, float& s3) {
    float t0 = __expf(fminf(-a0, 20.0f));
    float t1 = __expf(fminf(-a1, 20.0f));
    float t2 = __expf(fminf(-a2, 20.0f));
    float t3 = __expf(fminf(-a3, 20.0f));
    float d0 = 1.0f + t0, d1 = 1.0f + t1, d2 = 1.0f + t2, d3 = 1.0f + t3;
    float d01 = d0 * d1, d23 = d2 * d3;
    float rp = fast_rcp(d01 * d23);
    float q01 = d23 * rp, q23 = d01 * rp;        // 1/(d0*d1), 1/(d2*d3)
    s0 = a0 * (d1 * q01);
    s1 = a1 * (d0 * q01);
    s2 = a2 * (d3 * q23);
    s3 = a3 * (d2 * q23);
}

// 4-way tanh with ONE v_rcp: tanh(x) = 2/(1+exp(-2x)) - 1
__device__ __forceinline__ void tanh_quad(float x0, float x1, float x2, float x3,
                                          float& r0, float& r1, float& r2, float& r3) {
    float t0 = __expf(fminf(-2.0f * x0, 20.0f));
    float t1 = __expf(fminf(-2.0f * x1, 20.0f));
    float t2 = __expf(fminf(-2.0f * x2, 20.0f));
    float t3 = __expf(fminf(-2.0f * x3, 20.0f));
    float d0 = 1.0f + t0, d1 = 1.0f + t1, d2 = 1.0f + t2, d3 = 1.0f + t3;
    float d01 = d0 * d1, d23 = d2 * d3;
    float rp = fast_rcp(d01 * d23);
    float q01 = d23 * rp, q23 = d01 * rp;
    r0 = fmaf(2.0f, d1 * q01, -1.0f);
    r1 = fmaf(2.0f, d0 * q01, -1.0f);
    r2 = fmaf(2.0f, d3 * q23, -1.0f);
    r3 = fmaf(2.0f, d2 * q23, -1.0f);
}

__device__ __forceinline__ float softplus_f(float x) {
    float e = __expf(-fabsf(x));
    return fmaxf(x, 0.0f) + __logf(1.0f + e);
}

// ======================= d_ws layout (dword units) =======================
// [0, 1536):   A fragments, 12 mfma x 64 lanes x 2 dwords (f16x4 each)
//              0:g1 1:g2(logits replicated in all row-groups) 2:e1L1a 3:e1L1b
//              4:e1L2a 5:e1L2b 6:e2L1a 7:e2L1b 8:e2L2a 9:e2L2b 10:trunk 11:heads
// [1536,4096): bias C-in fragments, 10 x 64 x 4 f32
//              0:g1 1:g2(replicated) 2:e1L1a 3:e1L1b 4:e1L2 5:e2L1a 6:e2L1b 7:e2L2 8:trunk 9:heads
// [4096,6144): LN norm fragments, (expert*4+w) x 64 x 4 f32; w: 0:gC1 1:bnC1 2:gC2 3:bnC2
// =========================================================================

__device__ __forceinline__ float aval(int m, int row, int k,
                                      const float* gw1, const float* gw2,
                                      const float* e1w1, const float* e1w2,
                                      const float* e2w1, const float* e2w2,
                                      const float* tw, const float* sw, const float* hw) {
    switch (m) {
        case 0:  return (row < 8) ? gw1[k * 8 + row] : 0.0f;                     // g1: (16,8)
        case 1:  return ((row & 3) < 2 && k < 8) ? gw2[k * 2 + (row & 3)] : 0.0f; // g2 replicated per group
        case 2:  return e1w1[k * 24 + row];                                      // e1 L1 feats 0-15
        case 3:  return (row < 8) ? e1w1[k * 24 + 16 + row] : 0.0f;              // e1 L1 feats 16-23
        case 4:  return e1w2[k * 16 + row];                                      // e1 L2 k 0-15
        case 5:  return (k < 8) ? e1w2[(16 + k) * 16 + row] : 0.0f;              // e1 L2 k 16-23
        case 6:  return e2w1[k * 24 + row];
        case 7:  return (row < 8) ? e2w1[k * 24 + 16 + row] : 0.0f;
        case 8:  return e2w2[k * 16 + row];
        case 9:  return (k < 8) ? e2w2[(16 + k) * 16 + row] : 0.0f;
        case 10: return tw[k * 16 + row];                                        // trunk (16,16)
        default:                                                                 // heads
            if (row == 0) return sw[k];
            if (row == 1) return hw[2 * k + 0];
            if (row == 2) return hw[2 * k + 1];
            return 0.0f;
    }
}

__device__ __forceinline__ float bval(int bf, int row,
                                      const float* gb1, const float* gb2,
                                      const float* e1b1, const float* e1b2,
                                      const float* e2b1, const float* e2b2,
                                      const float* tb, const float* sb, const float* hb) {
    switch (bf) {
        case 0:  return (row < 8) ? gb1[row] : 0.0f;
        case 1:  return ((row & 3) < 2) ? gb2[row & 3] : 0.0f;    // replicated per group
        case 2:  return e1b1[row];
        case 3:  return (row < 8) ? e1b1[16 + row] : 0.0f;
        case 4:  return e1b2[row];
        case 5:  return e2b1[row];
        case 6:  return (row < 8) ? e2b1[16 + row] : 0.0f;
        case 7:  return e2b2[row];
        case 8:  return tb[row];
        default:
            if (row == 0) return sb[0];
            if (row == 1) return hb[0];
            if (row == 2) return hb[1];
            return 0.0f;
    }
}

__global__ void pack_frags(const float* __restrict__ gw1, const float* __restrict__ gb1,
                           const float* __restrict__ gw2, const float* __restrict__ gb2,
                           const float* __restrict__ e1w1, const float* __restrict__ e1b1,
                           const float* __restrict__ e1g, const float* __restrict__ e1bn,
                           const float* __restrict__ e1w2, const float* __restrict__ e1b2,
                           const float* __restrict__ e2w1, const float* __restrict__ e2b1,
                           const float* __restrict__ e2g, const float* __restrict__ e2bn,
                           const float* __restrict__ e2w2, const float* __restrict__ e2b2,
                           const float* __restrict__ tw, const float* __restrict__ tb,
                           const float* __restrict__ sw, const float* __restrict__ sb,
                           const float* __restrict__ hw, const float* __restrict__ hb,
                           u32* __restrict__ ws) {
    int t = blockIdx.x * blockDim.x + threadIdx.x;
    if (t < 1536) {
        // A fragments: one u32 (2 f16) per thread
        int m = t >> 7, rem = t & 127, lane = rem >> 1, d = rem & 1;
        int row = lane & 15, k0 = (lane >> 4) * 4 + 2 * d;
        float v0 = aval(m, row, k0,     gw1, gw2, e1w1, e1w2, e2w1, e2w2, tw, sw, hw);
        float v1 = aval(m, row, k0 + 1, gw1, gw2, e1w1, e1w2, e2w1, e2w2, tw, sw, hw);
        ws[t] = pk2(v0, v1);
    } else if (t < 4096) {
        int f = t - 1536;
        int bf = f >> 8, rem = f & 255, lane = rem >> 2, r = rem & 3;
        int row = (lane >> 4) * 4 + r;
        float v = bval(bf, row, gb1, gb2, e1b1, e1b2, e2b1, e2b2, tb, sb, hb);
        ((float*)ws)[t] = v;
    } else if (t < 6144) {
        int f = t - 4096;
        int nf = f >> 8, rem = f & 255, lane = rem >> 2, r = rem & 3;
        int e = nf >> 2, w = nf & 3, g_ = lane >> 4;
        const float* ge = e ? e2g : e1g;
        const float* bne = e ? e2bn : e1bn;
        float v;
        if (w < 2) {
            int feat = g_ * 4 + r;
            v = (w == 0) ? ge[feat] : bne[feat];
        } else {
            int feat = 16 + g_ * 4 + r;
            v = (g_ < 2) ? ((w == 2) ? ge[feat] : bne[feat]) : 0.0f;
        }
        ((float*)ws)[t] = v;
    }
}

// One expert: C-in carries biases; LN+silu glue; h (+)= scale * silu(L2)
template <bool FIRST>
__device__ __forceinline__ void expert_mfma(f16x4 A1a, f16x4 A1b, f16x4 A2a, f16x4 A2b,
                                            f32x4 b1a, f32x4 b1b, f32x4 b2,
                                            f32x4 gc1, f32x4 bc1, f32x4 gc2, f32x4 bc2,
                                            f16x4 Bx, float scale, f32x4& h) {
    f32x4 C1 = MFMA16(A1a, Bx, b1a);
    f32x4 C2 = MFMA16(A1b, Bx, b1b);
    float E = (C1[0] + C1[1]) + (C1[2] + C1[3]) + (C2[0] + C2[1]) + (C2[2] + C2[3]);
    float E2 = 0.0f;
#pragma unroll
    for (int i = 0; i < 4; ++i) E2 = fmaf(C1[i], C1[i], E2);
#pragma unroll
    for (int i = 0; i < 4; ++i) E2 = fmaf(C2[i], C2[i], E2);
    E  += __shfl_xor(E, 16);  E  += __shfl_xor(E, 32);
    E2 += __shfl_xor(E2, 16); E2 += __shfl_xor(E2, 32);
    float mu = E * (1.0f / 24.0f);
    float var = fmaf(E2, 1.0f / 24.0f, -mu * mu);
    float rstd = rsqrtf(var + LN_EPS);
    float n[8], sv[8];
#pragma unroll
    for (int i = 0; i < 4; ++i) n[i]     = fmaf((C1[i] - mu) * rstd, gc1[i], bc1[i]);
#pragma unroll
    for (int i = 0; i < 4; ++i) n[4 + i] = fmaf((C2[i] - mu) * rstd, gc2[i], bc2[i]);
    silu_quad(n[0], n[1], n[2], n[3], sv[0], sv[1], sv[2], sv[3]);
    silu_quad(n[4], n[5], n[6], n[7], sv[4], sv[5], sv[6], sv[7]);
    f16x4 B1 = mk4(sv[0], sv[1], sv[2], sv[3]);
    f16x4 B2 = mk4(sv[4], sv[5], sv[6], sv[7]);
    f32x4 O = MFMA16(A2a, B1, b2);
    O = MFMA16(A2b, B2, O);
    float so0, so1, so2, so3;
    silu_quad(O[0], O[1], O[2], O[3], so0, so1, so2, so3);
    if (FIRST) {
        h[0] = scale * so0; h[1] = scale * so1; h[2] = scale * so2; h[3] = scale * so3;
    } else {
        h[0] = fmaf(scale, so0, h[0]); h[1] = fmaf(scale, so1, h[1]);
        h[2] = fmaf(scale, so2, h[2]); h[3] = fmaf(scale, so3, h[3]);
    }
}

__global__ __launch_bounds__(256) void moe_mfma_kernel(const float* __restrict__ x,
                                                       const u32* __restrict__ ws,
                                                       float* __restrict__ out, int nrows) {
    const f16x4* Afr = (const f16x4*)ws;                 // [12*64]
    const float* wsf = (const float*)ws;
    const f32x4* Bfr = (const f32x4*)(wsf + 1536);       // [10*64]
    const f32x4* Nfr = (const f32x4*)(wsf + 4096);       // [8*64]

    int lane = threadIdx.x & 63;
    int g = lane >> 4, s = lane & 15;
    int wid = (blockIdx.x * blockDim.x + threadIdx.x) >> 6;
    int nw = (gridDim.x * blockDim.x) >> 6;

    // ---- preload all fragments to registers ----
    f16x4 Ag1 = Afr[0 * 64 + lane], Ag2 = Afr[1 * 64 + lane];
    f16x4 A1a = Afr[2 * 64 + lane], A1b = Afr[3 * 64 + lane];
    f16x4 A2a = Afr[4 * 64 + lane], A2b = Afr[5 * 64 + lane];
    f16x4 A3a = Afr[6 * 64 + lane], A3b = Afr[7 * 64 + lane];
    f16x4 A4a = Afr[8 * 64 + lane], A4b = Afr[9 * 64 + lane];
    f16x4 Atr = Afr[10 * 64 + lane], Ahd = Afr[11 * 64 + lane];
    f32x4 Bg1 = Bfr[0 * 64 + lane], Bg2 = Bfr[1 * 64 + lane];
    f32x4 Be1a = Bfr[2 * 64 + lane], Be1b = Bfr[3 * 64 + lane], Be1o = Bfr[4 * 64 + lane];
    f32x4 Be2a = Bfr[5 * 64 + lane], Be2b = Bfr[6 * 64 + lane], Be2o = Bfr[7 * 64 + lane];
    f32x4 Btr = Bfr[8 * 64 + lane], Bhd = Bfr[9 * 64 + lane];
    f32x4 G1c1 = Nfr[0 * 64 + lane], B1c1 = Nfr[1 * 64 + lane];
    f32x4 G1c2 = Nfr[2 * 64 + lane], B1c2 = Nfr[3 * 64 + lane];
    f32x4 G2c1 = Nfr[4 * 64 + lane], B2c1 = Nfr[5 * 64 + lane];
    f32x4 G2c2 = Nfr[6 * 64 + lane], B2c2 = Nfr[7 * 64 + lane];

    int ntiles = (nrows + 15) >> 4;
    int nclamp = nrows - 1;

    // ---- prefetch first tile's x ----
    f32x4 xv;
    {
        int r0 = wid * 16 + s;
        int rc = r0 < nrows ? r0 : nclamp;
        xv = *(const f32x4*)(x + (size_t)rc * 16 + g * 4);
    }

    for (int tile = wid; tile < ntiles; tile += nw) {
        // ---- issue next tile's x load (latency hides under this tile's compute) ----
        f32x4 xnext;
        {
            int tn = tile + nw;
            int r0n = (tn < ntiles ? tn : tile) * 16 + s;
            int rcn = r0n < nrows ? r0n : nclamp;
            xnext = *(const f32x4*)(x + (size_t)rcn * 16 + g * 4);
        }

        int r0 = tile * 16 + s;
        f16x4 Bx = mk4(xv[0], xv[1], xv[2], xv[3]);

        // ---- gate (logits replicated into every row-group: no cross-lane needed) ----
        f32x4 Cg = MFMA16(Ag1, Bx, Bg1);
        float t0, t1, t2, t3;
        tanh_quad(Cg[0], Cg[1], Cg[2], Cg[3], t0, t1, t2, t3);
        f16x4 Bt = mk4(t0, t1, t2, t3);
        f32x4 Cl = MFMA16(Ag2, Bt, Bg2);
        float w0 = fast_rcp(1.0f + __expf(Cl[1] - Cl[0]));   // sigmoid(l0 - l1)
        float w1 = 1.0f - w0;

        // ---- experts ----
        f32x4 h;
        expert_mfma<true >(A1a, A1b, A2a, A2b, Be1a, Be1b, Be1o, G1c1, B1c1, G1c2, B1c2, Bx, w0, h);
        expert_mfma<false>(A3a, A3b, A4a, A4b, Be2a, Be2b, Be2o, G2c1, B2c1, G2c2, B2c2, Bx, w1, h);

        // ---- trunk ----
        f16x4 Bh = mk4(h[0], h[1], h[2], h[3]);
        f32x4 Ct = MFMA16(Atr, Bh, Btr);
        float u0, u1, u2, u3;
        silu_quad(Ct[0], Ct[1], Ct[2], Ct[3], u0, u1, u2, u3);
        f16x4 Bu = mk4(u0, u1, u2, u3);

        // ---- heads ----
        f32x4 Ch = MFMA16(Ahd, Bu, Bhd);
        if (g == 0 && r0 < nrows) {
            float strain = Ch[0];
            float tens = Ch[1];
            float yld = tens - softplus_f(Ch[2]);
            size_t o = (size_t)r0 * 3;
            out[o + 0] = strain;
            out[o + 1] = tens;
            out[o + 2] = yld;
        }

        xv = xnext;
    }
}

extern "C" void kernel_launch(void* const* d_in, const int* in_sizes, int n_in,
                              void* d_out, int out_size, void* d_ws, size_t ws_size,
                              hipStream_t stream) {
    const float* x    = (const float*)d_in[0];
    const float* gw1  = (const float*)d_in[1];
    const float* gb1  = (const float*)d_in[2];
    const float* gw2  = (const float*)d_in[3];
    const float* gb2  = (const float*)d_in[4];
    const float* e1w1 = (const float*)d_in[5];
    const float* e1b1 = (const float*)d_in[6];
    const float* e1g  = (const float*)d_in[7];
    const float* e1bn = (const float*)d_in[8];
    const float* e1w2 = (const float*)d_in[9];
    const float* e1b2 = (const float*)d_in[10];
    const float* e2w1 = (const float*)d_in[11];
    const float* e2b1 = (const float*)d_in[12];
    const float* e2g  = (const float*)d_in[13];
    const float* e2bn = (const float*)d_in[14];
    const float* e2w2 = (const float*)d_in[15];
    const float* e2b2 = (const float*)d_in[16];
    const float* tw   = (const float*)d_in[17];
    const float* tb   = (const float*)d_in[18];
    const float* sw   = (const float*)d_in[19];
    const float* sb   = (const float*)d_in[20];
    const float* hw   = (const float*)d_in[21];
    const float* hb   = (const float*)d_in[22];
    float* out = (float*)d_out;
    u32* ws = (u32*)d_ws;

    pack_frags<<<24, 256, 0, stream>>>(gw1, gb1, gw2, gb2,
                                       e1w1, e1b1, e1g, e1bn, e1w2, e1b2,
                                       e2w1, e2b1, e2g, e2bn, e2w2, e2b2,
                                       tw, tb, sw, sb, hw, hb, ws);

    int nrows = in_sizes[0] / 16;
    moe_mfma_kernel<<<2048, 256, 0, stream>>>(x, ws, out, nrows);
}

// Round 12
// 120.876 us; speedup vs baseline: 1.0252x; 1.0252x over previous
//
#include <hip/hip_runtime.h>

#define LN_EPS 1e-5f

typedef _Float16 f16x4 __attribute__((ext_vector_type(4)));
typedef float f32x4 __attribute__((ext_vector_type(4)));
typedef unsigned int u32;
typedef u32 u32x2 __attribute__((ext_vector_type(2)));

#if defined(__HIP_DEVICE_COMPILE__)
#  if __has_builtin(__builtin_amdgcn_mfma_f32_16x16x16f16)
#    define MFMA16(a, b, c) __builtin_amdgcn_mfma_f32_16x16x16f16(a, b, c, 0, 0, 0)
#  elif __has_builtin(__builtin_amdgcn_mfma_f32_16x16x16_f16)
#    define MFMA16(a, b, c) __builtin_amdgcn_mfma_f32_16x16x16_f16(a, b, c, 0, 0, 0)
#  else
#    error "no 16x16x16 f16 mfma builtin on device"
#  endif
#else
#  define MFMA16(a, b, c) (c)   /* host pass: parse-only dummy, never executed */
#endif

__device__ __forceinline__ float fast_rcp(float x) { return __builtin_amdgcn_rcpf(x); }

__device__ __forceinline__ u32 pk2(float a, float b) {
    return __builtin_bit_cast(u32, __builtin_amdgcn_cvt_pkrtz(a, b));
}
__device__ __forceinline__ f16x4 mk4(float a, float b, float c, float d) {
    u32x2 t = {pk2(a, b), pk2(c, d)};
    return __builtin_bit_cast(f16x4, t);
}

// 4-way silu with ONE v_rcp. exp-arg clamp 20: (1+e^20)^4 ~ 5.5e34 < f32max.
__device__ __forceinline__ void silu_quad(float a0, float a1, float a2, float a3,
                                          float& s0, float& s1, float& s2, float& s3) {
    float t0 = __expf(fminf(-a0, 20.0f));
    float t1 = __expf(fminf(-a1, 20.0f));
    float t2 = __expf(fminf(-a2, 20.0f));
    float t3 = __expf(fminf(-a3, 20.0f));
    float d0 = 1.0f + t0, d1 = 1.0f + t1, d2 = 1.0f + t2, d3 = 1.0f + t3;
    float d01 = d0 * d1, d23 = d2 * d3;
    float rp = fast_rcp(d01 * d23);
    float q01 = d23 * rp, q23 = d01 * rp;
    s0 = a0 * (d1 * q01);
    s1 = a1 * (d0 * q01);
    s2 = a2 * (d3 * q23);
    s3 = a3 * (d2 * q23);
}

// 4-way tanh with ONE v_rcp: tanh(x) = 2/(1+exp(-2x)) - 1
__device__ __forceinline__ void tanh_quad(float x0, float x1, float x2, float x3,
                                          float& r0, float& r1, float& r2, float& r3) {
    float t0 = __expf(fminf(-2.0f * x0, 20.0f));
    float t1 = __expf(fminf(-2.0f * x1, 20.0f));
    float t2 = __expf(fminf(-2.0f * x2, 20.0f));
    float t3 = __expf(fminf(-2.0f * x3, 20.0f));
    float d0 = 1.0f + t0, d1 = 1.0f + t1, d2 = 1.0f + t2, d3 = 1.0f + t3;
    float d01 = d0 * d1, d23 = d2 * d3;
    float rp = fast_rcp(d01 * d23);
    float q01 = d23 * rp, q23 = d01 * rp;
    r0 = fmaf(2.0f, d1 * q01, -1.0f);
    r1 = fmaf(2.0f, d0 * q01, -1.0f);
    r2 = fmaf(2.0f, d3 * q23, -1.0f);
    r3 = fmaf(2.0f, d2 * q23, -1.0f);
}

__device__ __forceinline__ float softplus_f(float x) {
    float e = __expf(-fabsf(x));
    return fmaxf(x, 0.0f) + __logf(1.0f + e);
}

// ======================= d_ws layout (dword units) =======================
// [0, 1536):   A fragments, 12 mfma x 64 lanes x 2 dwords (f16x4 each)
//              0:g1 1:g2(logits replicated) 2:e1L1a 3:e1L1b 4:e1L2a 5:e1L2b
//              6:e2L1a 7:e2L1b 8:e2L2a 9:e2L2b 10:trunk 11:heads
// [1536,4096): bias C-in fragments, 10 x 64 x 4 f32
// [4096,6144): LN norm fragments, (expert*4+w) x 64 x 4 f32
// =========================================================================

__device__ __forceinline__ float aval(int m, int row, int k,
                                      const float* gw1, const float* gw2,
                                      const float* e1w1, const float* e1w2,
                                      const float* e2w1, const float* e2w2,
                                      const float* tw, const float* sw, const float* hw) {
    switch (m) {
        case 0:  return (row < 8) ? gw1[k * 8 + row] : 0.0f;
        case 1:  return ((row & 3) < 2 && k < 8) ? gw2[k * 2 + (row & 3)] : 0.0f;
        case 2:  return e1w1[k * 24 + row];
        case 3:  return (row < 8) ? e1w1[k * 24 + 16 + row] : 0.0f;
        case 4:  return e1w2[k * 16 + row];
        case 5:  return (k < 8) ? e1w2[(16 + k) * 16 + row] : 0.0f;
        case 6:  return e2w1[k * 24 + row];
        case 7:  return (row < 8) ? e2w1[k * 24 + 16 + row] : 0.0f;
        case 8:  return e2w2[k * 16 + row];
        case 9:  return (k < 8) ? e2w2[(16 + k) * 16 + row] : 0.0f;
        case 10: return tw[k * 16 + row];
        default:
            if (row == 0) return sw[k];
            if (row == 1) return hw[2 * k + 0];
            if (row == 2) return hw[2 * k + 1];
            return 0.0f;
    }
}

__device__ __forceinline__ float bval(int bf, int row,
                                      const float* gb1, const float* gb2,
                                      const float* e1b1, const float* e1b2,
                                      const float* e2b1, const float* e2b2,
                                      const float* tb, const float* sb, const float* hb) {
    switch (bf) {
        case 0:  return (row < 8) ? gb1[row] : 0.0f;
        case 1:  return ((row & 3) < 2) ? gb2[row & 3] : 0.0f;
        case 2:  return e1b1[row];
        case 3:  return (row < 8) ? e1b1[16 + row] : 0.0f;
        case 4:  return e1b2[row];
        case 5:  return e2b1[row];
        case 6:  return (row < 8) ? e2b1[16 + row] : 0.0f;
        case 7:  return e2b2[row];
        case 8:  return tb[row];
        default:
            if (row == 0) return sb[0];
            if (row == 1) return hb[0];
            if (row == 2) return hb[1];
            return 0.0f;
    }
}

__global__ void pack_frags(const float* __restrict__ gw1, const float* __restrict__ gb1,
                           const float* __restrict__ gw2, const float* __restrict__ gb2,
                           const float* __restrict__ e1w1, const float* __restrict__ e1b1,
                           const float* __restrict__ e1g, const float* __restrict__ e1bn,
                           const float* __restrict__ e1w2, const float* __restrict__ e1b2,
                           const float* __restrict__ e2w1, const float* __restrict__ e2b1,
                           const float* __restrict__ e2g, const float* __restrict__ e2bn,
                           const float* __restrict__ e2w2, const float* __restrict__ e2b2,
                           const float* __restrict__ tw, const float* __restrict__ tb,
                           const float* __restrict__ sw, const float* __restrict__ sb,
                           const float* __restrict__ hw, const float* __restrict__ hb,
                           u32* __restrict__ ws) {
    int t = blockIdx.x * blockDim.x + threadIdx.x;
    if (t < 1536) {
        int m = t >> 7, rem = t & 127, lane = rem >> 1, d = rem & 1;
        int row = lane & 15, k0 = (lane >> 4) * 4 + 2 * d;
        float v0 = aval(m, row, k0,     gw1, gw2, e1w1, e1w2, e2w1, e2w2, tw, sw, hw);
        float v1 = aval(m, row, k0 + 1, gw1, gw2, e1w1, e1w2, e2w1, e2w2, tw, sw, hw);
        ws[t] = pk2(v0, v1);
    } else if (t < 4096) {
        int f = t - 1536;
        int bf = f >> 8, rem = f & 255, lane = rem >> 2, r = rem & 3;
        int row = (lane >> 4) * 4 + r;
        float v = bval(bf, row, gb1, gb2, e1b1, e1b2, e2b1, e2b2, tb, sb, hb);
        ((float*)ws)[t] = v;
    } else if (t < 6144) {
        int f = t - 4096;
        int nf = f >> 8, rem = f & 255, lane = rem >> 2, r = rem & 3;
        int e = nf >> 2, w = nf & 3, g_ = lane >> 4;
        const float* ge = e ? e2g : e1g;
        const float* bne = e ? e2bn : e1bn;
        float v;
        if (w < 2) {
            int feat = g_ * 4 + r;
            v = (w == 0) ? ge[feat] : bne[feat];
        } else {
            int feat = 16 + g_ * 4 + r;
            v = (g_ < 2) ? ((w == 2) ? ge[feat] : bne[feat]) : 0.0f;
        }
        ((float*)ws)[t] = v;
    }
}

// One expert, TWO sample-tiles: every A/bias/LN fragment value is used twice.
template <bool FIRST>
__device__ __forceinline__ void expert_mfma2(f16x4 A1a, f16x4 A1b, f16x4 A2a, f16x4 A2b,
                                             f32x4 b1a, f32x4 b1b, f32x4 b2,
                                             f32x4 gc1, f32x4 bc1, f32x4 gc2, f32x4 bc2,
                                             f16x4 Bx0, f16x4 Bx1,
                                             float sc0, float sc1,
                                             f32x4& h0, f32x4& h1) {
    f32x4 C1_0 = MFMA16(A1a, Bx0, b1a);
    f32x4 C1_1 = MFMA16(A1a, Bx1, b1a);
    f32x4 C2_0 = MFMA16(A1b, Bx0, b1b);
    f32x4 C2_1 = MFMA16(A1b, Bx1, b1b);

    float E0 = 0.0f, E20 = 0.0f, E1 = 0.0f, E21 = 0.0f;
#pragma unroll
    for (int i = 0; i < 4; ++i) {
        E0 += C1_0[i] + C2_0[i];
        E1 += C1_1[i] + C2_1[i];
        E20 = fmaf(C1_0[i], C1_0[i], fmaf(C2_0[i], C2_0[i], E20));
        E21 = fmaf(C1_1[i], C1_1[i], fmaf(C2_1[i], C2_1[i], E21));
    }
    E0  += __shfl_xor(E0, 16);  E0  += __shfl_xor(E0, 32);
    E1  += __shfl_xor(E1, 16);  E1  += __shfl_xor(E1, 32);
    E20 += __shfl_xor(E20, 16); E20 += __shfl_xor(E20, 32);
    E21 += __shfl_xor(E21, 16); E21 += __shfl_xor(E21, 32);
    float mu0 = E0 * (1.0f / 24.0f), mu1 = E1 * (1.0f / 24.0f);
    float rstd0 = rsqrtf(fmaf(E20, 1.0f / 24.0f, -mu0 * mu0) + LN_EPS);
    float rstd1 = rsqrtf(fmaf(E21, 1.0f / 24.0f, -mu1 * mu1) + LN_EPS);

    float n0[8], n1[8], sv0[8], sv1[8];
#pragma unroll
    for (int i = 0; i < 4; ++i) {
        n0[i]     = fmaf((C1_0[i] - mu0) * rstd0, gc1[i], bc1[i]);
        n1[i]     = fmaf((C1_1[i] - mu1) * rstd1, gc1[i], bc1[i]);
        n0[4 + i] = fmaf((C2_0[i] - mu0) * rstd0, gc2[i], bc2[i]);
        n1[4 + i] = fmaf((C2_1[i] - mu1) * rstd1, gc2[i], bc2[i]);
    }
    silu_quad(n0[0], n0[1], n0[2], n0[3], sv0[0], sv0[1], sv0[2], sv0[3]);
    silu_quad(n0[4], n0[5], n0[6], n0[7], sv0[4], sv0[5], sv0[6], sv0[7]);
    silu_quad(n1[0], n1[1], n1[2], n1[3], sv1[0], sv1[1], sv1[2], sv1[3]);
    silu_quad(n1[4], n1[5], n1[6], n1[7], sv1[4], sv1[5], sv1[6], sv1[7]);
    f16x4 B1_0 = mk4(sv0[0], sv0[1], sv0[2], sv0[3]);
    f16x4 B2_0 = mk4(sv0[4], sv0[5], sv0[6], sv0[7]);
    f16x4 B1_1 = mk4(sv1[0], sv1[1], sv1[2], sv1[3]);
    f16x4 B2_1 = mk4(sv1[4], sv1[5], sv1[6], sv1[7]);

    f32x4 O0 = MFMA16(A2a, B1_0, b2);
    f32x4 O1 = MFMA16(A2a, B1_1, b2);
    O0 = MFMA16(A2b, B2_0, O0);
    O1 = MFMA16(A2b, B2_1, O1);

    float p0[4], p1[4];
    silu_quad(O0[0], O0[1], O0[2], O0[3], p0[0], p0[1], p0[2], p0[3]);
    silu_quad(O1[0], O1[1], O1[2], O1[3], p1[0], p1[1], p1[2], p1[3]);
#pragma unroll
    for (int i = 0; i < 4; ++i) {
        if (FIRST) {
            h0[i] = sc0 * p0[i];
            h1[i] = sc1 * p1[i];
        } else {
            h0[i] = fmaf(sc0, p0[i], h0[i]);
            h1[i] = fmaf(sc1, p1[i], h1[i]);
        }
    }
}

__global__ __launch_bounds__(256) void moe_mfma_kernel(const float* __restrict__ x,
                                                       const u32* __restrict__ ws,
                                                       float* __restrict__ out, int nrows) {
    const f16x4* Afr = (const f16x4*)ws;
    const float* wsf = (const float*)ws;
    const f32x4* Bfr = (const f32x4*)(wsf + 1536);
    const f32x4* Nfr = (const f32x4*)(wsf + 4096);

    int lane = threadIdx.x & 63;
    int g = lane >> 4, s = lane & 15;
    int wid = (blockIdx.x * blockDim.x + threadIdx.x) >> 6;
    int nw = (gridDim.x * blockDim.x) >> 6;

    f16x4 Ag1 = Afr[0 * 64 + lane], Ag2 = Afr[1 * 64 + lane];
    f16x4 A1a = Afr[2 * 64 + lane], A1b = Afr[3 * 64 + lane];
    f16x4 A2a = Afr[4 * 64 + lane], A2b = Afr[5 * 64 + lane];
    f16x4 A3a = Afr[6 * 64 + lane], A3b = Afr[7 * 64 + lane];
    f16x4 A4a = Afr[8 * 64 + lane], A4b = Afr[9 * 64 + lane];
    f16x4 Atr = Afr[10 * 64 + lane], Ahd = Afr[11 * 64 + lane];
    f32x4 Bg1 = Bfr[0 * 64 + lane], Bg2 = Bfr[1 * 64 + lane];
    f32x4 Be1a = Bfr[2 * 64 + lane], Be1b = Bfr[3 * 64 + lane], Be1o = Bfr[4 * 64 + lane];
    f32x4 Be2a = Bfr[5 * 64 + lane], Be2b = Bfr[6 * 64 + lane], Be2o = Bfr[7 * 64 + lane];
    f32x4 Btr = Bfr[8 * 64 + lane], Bhd = Bfr[9 * 64 + lane];
    f32x4 G1c1 = Nfr[0 * 64 + lane], B1c1 = Nfr[1 * 64 + lane];
    f32x4 G1c2 = Nfr[2 * 64 + lane], B1c2 = Nfr[3 * 64 + lane];
    f32x4 G2c1 = Nfr[4 * 64 + lane], B2c1 = Nfr[5 * 64 + lane];
    f32x4 G2c2 = Nfr[6 * 64 + lane], B2c2 = Nfr[7 * 64 + lane];

    int ntiles = (nrows + 15) >> 4;
    int nclamp = nrows - 1;

    // pair loop: wave handles tiles (2p, 2p+1)
    auto loadx = [&](int tile) -> f32x4 {
        int r = tile * 16 + s;
        int rc = r < nrows ? r : nclamp;
        return *(const f32x4*)(x + (size_t)rc * 16 + g * 4);
    };

    int p0 = 2 * wid;
    f32x4 xv0, xv1;
    if (p0 < ntiles) {
        xv0 = loadx(p0);
        xv1 = loadx(p0 + 1 < ntiles ? p0 + 1 : p0);
    }

    for (int tp = p0; tp < ntiles; tp += 2 * nw) {
        // prefetch next pair
        int tnp = tp + 2 * nw;
        f32x4 xn0, xn1;
        {
            int t0n = tnp < ntiles ? tnp : tp;
            int t1n = tnp + 1 < ntiles ? tnp + 1 : t0n;
            xn0 = loadx(t0n);
            xn1 = loadx(t1n);
        }

        int r0 = tp * 16 + s;
        int r1 = (tp + 1) * 16 + s;
        f16x4 Bx0 = mk4(xv0[0], xv0[1], xv0[2], xv0[3]);
        f16x4 Bx1 = mk4(xv1[0], xv1[1], xv1[2], xv1[3]);

        // ---- gate (both tiles share Ag1/Ag2/Bg1/Bg2) ----
        f32x4 Cg0 = MFMA16(Ag1, Bx0, Bg1);
        f32x4 Cg1 = MFMA16(Ag1, Bx1, Bg1);
        float a0, a1, a2, a3, b0, b1, b2_, b3;
        tanh_quad(Cg0[0], Cg0[1], Cg0[2], Cg0[3], a0, a1, a2, a3);
        tanh_quad(Cg1[0], Cg1[1], Cg1[2], Cg1[3], b0, b1, b2_, b3);
        f16x4 Bt0 = mk4(a0, a1, a2, a3);
        f16x4 Bt1 = mk4(b0, b1, b2_, b3);
        f32x4 Cl0 = MFMA16(Ag2, Bt0, Bg2);
        f32x4 Cl1 = MFMA16(Ag2, Bt1, Bg2);
        float w00 = fast_rcp(1.0f + __expf(Cl0[1] - Cl0[0]));
        float w01 = 1.0f - w00;
        float w10 = fast_rcp(1.0f + __expf(Cl1[1] - Cl1[0]));
        float w11 = 1.0f - w10;

        // ---- experts ----
        f32x4 h0, h1;
        expert_mfma2<true >(A1a, A1b, A2a, A2b, Be1a, Be1b, Be1o,
                            G1c1, B1c1, G1c2, B1c2, Bx0, Bx1, w00, w10, h0, h1);
        expert_mfma2<false>(A3a, A3b, A4a, A4b, Be2a, Be2b, Be2o,
                            G2c1, B2c1, G2c2, B2c2, Bx0, Bx1, w01, w11, h0, h1);

        // ---- trunk ----
        f16x4 Bh0 = mk4(h0[0], h0[1], h0[2], h0[3]);
        f16x4 Bh1 = mk4(h1[0], h1[1], h1[2], h1[3]);
        f32x4 Ct0 = MFMA16(Atr, Bh0, Btr);
        f32x4 Ct1 = MFMA16(Atr, Bh1, Btr);
        float u0[4], u1[4];
        silu_quad(Ct0[0], Ct0[1], Ct0[2], Ct0[3], u0[0], u0[1], u0[2], u0[3]);
        silu_quad(Ct1[0], Ct1[1], Ct1[2], Ct1[3], u1[0], u1[1], u1[2], u1[3]);
        f16x4 Bu0 = mk4(u0[0], u0[1], u0[2], u0[3]);
        f16x4 Bu1 = mk4(u1[0], u1[1], u1[2], u1[3]);

        // ---- heads ----
        f32x4 Ch0 = MFMA16(Ahd, Bu0, Bhd);
        f32x4 Ch1 = MFMA16(Ahd, Bu1, Bhd);
        if (g == 0) {
            if (r0 < nrows) {
                float yld = Ch0[1] - softplus_f(Ch0[2]);
                size_t o = (size_t)r0 * 3;
                out[o + 0] = Ch0[0];
                out[o + 1] = Ch0[1];
                out[o + 2] = yld;
            }
            if (r1 < nrows) {
                float yld = Ch1[1] - softplus_f(Ch1[2]);
                size_t o = (size_t)r1 * 3;
                out[o + 0] = Ch1[0];
                out[o + 1] = Ch1[1];
                out[o + 2] = yld;
            }
        }

        xv0 = xn0;
        xv1 = xn1;
    }
}

extern "C" void kernel_launch(void* const* d_in, const int* in_sizes, int n_in,
                              void* d_out, int out_size, void* d_ws, size_t ws_size,
                              hipStream_t stream) {
    const float* x    = (const float*)d_in[0];
    const float* gw1  = (const float*)d_in[1];
    const float* gb1  = (const float*)d_in[2];
    const float* gw2  = (const float*)d_in[3];
    const float* gb2  = (const float*)d_in[4];
    const float* e1w1 = (const float*)d_in[5];
    const float* e1b1 = (const float*)d_in[6];
    const float* e1g  = (const float*)d_in[7];
    const float* e1bn = (const float*)d_in[8];
    const float* e1w2 = (const float*)d_in[9];
    const float* e1b2 = (const float*)d_in[10];
    const float* e2w1 = (const float*)d_in[11];
    const float* e2b1 = (const float*)d_in[12];
    const float* e2g  = (const float*)d_in[13];
    const float* e2bn = (const float*)d_in[14];
    const float* e2w2 = (const float*)d_in[15];
    const float* e2b2 = (const float*)d_in[16];
    const float* tw   = (const float*)d_in[17];
    const float* tb   = (const float*)d_in[18];
    const float* sw   = (const float*)d_in[19];
    const float* sb   = (const float*)d_in[20];
    const float* hw   = (const float*)d_in[21];
    const float* hb   = (const float*)d_in[22];
    float* out = (float*)d_out;
    u32* ws = (u32*)d_ws;

    pack_frags<<<24, 256, 0, stream>>>(gw1, gb1, gw2, gb2,
                                       e1w1, e1b1, e1g, e1bn, e1w2, e1b2,
                                       e2w1, e2b1, e2g, e2bn, e2w2, e2b2,
                                       tw, tb, sw, sb, hw, hb, ws);

    int nrows = in_sizes[0] / 16;
    moe_mfma_kernel<<<2048, 256, 0, stream>>>(x, ws, out, nrows);
}

// Round 13
// 120.552 us; speedup vs baseline: 1.0280x; 1.0027x over previous
//
#include <hip/hip_runtime.h>

#define LN_EPS 1e-5f

typedef _Float16 f16x4 __attribute__((ext_vector_type(4)));
typedef float f32x4 __attribute__((ext_vector_type(4)));
typedef unsigned int u32;
typedef u32 u32x2 __attribute__((ext_vector_type(2)));

#if defined(__HIP_DEVICE_COMPILE__)
#  if __has_builtin(__builtin_amdgcn_mfma_f32_16x16x16f16)
#    define MFMA16(a, b, c) __builtin_amdgcn_mfma_f32_16x16x16f16(a, b, c, 0, 0, 0)
#  elif __has_builtin(__builtin_amdgcn_mfma_f32_16x16x16_f16)
#    define MFMA16(a, b, c) __builtin_amdgcn_mfma_f32_16x16x16_f16(a, b, c, 0, 0, 0)
#  else
#    error "no 16x16x16 f16 mfma builtin on device"
#  endif
#else
#  define MFMA16(a, b, c) (c)   /* host pass: parse-only dummy, never executed */
#endif

__device__ __forceinline__ float fast_rcp(float x) { return __builtin_amdgcn_rcpf(x); }

__device__ __forceinline__ u32 pk2(float a, float b) {
    return __builtin_bit_cast(u32, __builtin_amdgcn_cvt_pkrtz(a, b));
}
__device__ __forceinline__ f16x4 mk4(float a, float b, float c, float d) {
    u32x2 t = {pk2(a, b), pk2(c, d)};
    return __builtin_bit_cast(f16x4, t);
}

// 4-way silu with ONE v_rcp. exp-arg clamp 20: (1+e^20)^4 ~ 5.5e34 < f32max.
__device__ __forceinline__ void silu_quad(float a0, float a1, float a2, float a3,
                                          float& s0, float& s1, float& s2, float& s3) {
    float t0 = __expf(fminf(-a0, 20.0f));
    float t1 = __expf(fminf(-a1, 20.0f));
    float t2 = __expf(fminf(-a2, 20.0f));
    float t3 = __expf(fminf(-a3, 20.0f));
    float d0 = 1.0f + t0, d1 = 1.0f + t1, d2 = 1.0f + t2, d3 = 1.0f + t3;
    float d01 = d0 * d1, d23 = d2 * d3;
    float rp = fast_rcp(d01 * d23);
    float q01 = d23 * rp, q23 = d01 * rp;
    s0 = a0 * (d1 * q01);
    s1 = a1 * (d0 * q01);
    s2 = a2 * (d3 * q23);
    s3 = a3 * (d2 * q23);
}

// 4-way tanh with ONE v_rcp: tanh(x) = 2/(1+exp(-2x)) - 1
__device__ __forceinline__ void tanh_quad(float x0, float x1, float x2, float x3,
                                          float& r0, float& r1, float& r2, float& r3) {
    float t0 = __expf(fminf(-2.0f * x0, 20.0f));
    float t1 = __expf(fminf(-2.0f * x1, 20.0f));
    float t2 = __expf(fminf(-2.0f * x2, 20.0f));
    float t3 = __expf(fminf(-2.0f * x3, 20.0f));
    float d0 = 1.0f + t0, d1 = 1.0f + t1, d2 = 1.0f + t2, d3 = 1.0f + t3;
    float d01 = d0 * d1, d23 = d2 * d3;
    float rp = fast_rcp(d01 * d23);
    float q01 = d23 * rp, q23 = d01 * rp;
    r0 = fmaf(2.0f, d1 * q01, -1.0f);
    r1 = fmaf(2.0f, d0 * q01, -1.0f);
    r2 = fmaf(2.0f, d3 * q23, -1.0f);
    r3 = fmaf(2.0f, d2 * q23, -1.0f);
}

__device__ __forceinline__ float softplus_f(float x) {
    float e = __expf(-fabsf(x));
    return fmaxf(x, 0.0f) + __logf(1.0f + e);
}

// ======================= d_ws layout (dword units) =======================
// [0, 1536):   A fragments, 12 mfma x 64 lanes x 2 dwords (f16x4 each)
//              0:g1 1:g2(logits replicated) 2:e1L1a 3:e1L1b(+murow@8) 4:e1L2a 5:e1L2b
//              6:e2L1a 7:e2L1b(+murow@8) 8:e2L2a 9:e2L2b 10:trunk 11:heads
// [1536,4096): bias C-in fragments, 10 x 64 x 4 f32 (L1b rows get mean-bias@8)
// [4096,6144): LN norm fragments, (expert*4+w) x 64 x 4 f32
// =========================================================================

__device__ __forceinline__ float aval(int m, int row, int k,
                                      const float* gw1, const float* gw2,
                                      const float* e1w1, const float* e1w2,
                                      const float* e2w1, const float* e2w2,
                                      const float* tw, const float* sw, const float* hw) {
    switch (m) {
        case 0:  return (row < 8) ? gw1[k * 8 + row] : 0.0f;
        case 1:  return ((row & 3) < 2 && k < 8) ? gw2[k * 2 + (row & 3)] : 0.0f;
        case 2:  return e1w1[k * 24 + row];
        case 3: {
            if (row < 8) return e1w1[k * 24 + 16 + row];
            if (row == 8) {   // mu-row: (1/24) * column sums of W1
                float t = 0.0f;
                for (int j = 0; j < 24; ++j) t += e1w1[k * 24 + j];
                return t * (1.0f / 24.0f);
            }
            return 0.0f;
        }
        case 4:  return e1w2[k * 16 + row];
        case 5:  return (k < 8) ? e1w2[(16 + k) * 16 + row] : 0.0f;
        case 6:  return e2w1[k * 24 + row];
        case 7: {
            if (row < 8) return e2w1[k * 24 + 16 + row];
            if (row == 8) {
                float t = 0.0f;
                for (int j = 0; j < 24; ++j) t += e2w1[k * 24 + j];
                return t * (1.0f / 24.0f);
            }
            return 0.0f;
        }
        case 8:  return e2w2[k * 16 + row];
        case 9:  return (k < 8) ? e2w2[(16 + k) * 16 + row] : 0.0f;
        case 10: return tw[k * 16 + row];
        default:
            if (row == 0) return sw[k];
            if (row == 1) return hw[2 * k + 0];
            if (row == 2) return hw[2 * k + 1];
            return 0.0f;
    }
}

__device__ __forceinline__ float bval(int bf, int row,
                                      const float* gb1, const float* gb2,
                                      const float* e1b1, const float* e1b2,
                                      const float* e2b1, const float* e2b2,
                                      const float* tb, const float* sb, const float* hb) {
    switch (bf) {
        case 0:  return (row < 8) ? gb1[row] : 0.0f;
        case 1:  return ((row & 3) < 2) ? gb2[row & 3] : 0.0f;
        case 2:  return e1b1[row];
        case 3: {
            if (row < 8) return e1b1[16 + row];
            if (row == 8) {   // mean bias for mu-row
                float t = 0.0f;
                for (int j = 0; j < 24; ++j) t += e1b1[j];
                return t * (1.0f / 24.0f);
            }
            return 0.0f;
        }
        case 4:  return e1b2[row];
        case 5:  return e2b1[row];
        case 6: {
            if (row < 8) return e2b1[16 + row];
            if (row == 8) {
                float t = 0.0f;
                for (int j = 0; j < 24; ++j) t += e2b1[j];
                return t * (1.0f / 24.0f);
            }
            return 0.0f;
        }
        case 7:  return e2b2[row];
        case 8:  return tb[row];
        default:
            if (row == 0) return sb[0];
            if (row == 1) return hb[0];
            if (row == 2) return hb[1];
            return 0.0f;
    }
}

__global__ void pack_frags(const float* __restrict__ gw1, const float* __restrict__ gb1,
                           const float* __restrict__ gw2, const float* __restrict__ gb2,
                           const float* __restrict__ e1w1, const float* __restrict__ e1b1,
                           const float* __restrict__ e1g, const float* __restrict__ e1bn,
                           const float* __restrict__ e1w2, const float* __restrict__ e1b2,
                           const float* __restrict__ e2w1, const float* __restrict__ e2b1,
                           const float* __restrict__ e2g, const float* __restrict__ e2bn,
                           const float* __restrict__ e2w2, const float* __restrict__ e2b2,
                           const float* __restrict__ tw, const float* __restrict__ tb,
                           const float* __restrict__ sw, const float* __restrict__ sb,
                           const float* __restrict__ hw, const float* __restrict__ hb,
                           u32* __restrict__ ws) {
    int t = blockIdx.x * blockDim.x + threadIdx.x;
    if (t < 1536) {
        int m = t >> 7, rem = t & 127, lane = rem >> 1, d = rem & 1;
        int row = lane & 15, k0 = (lane >> 4) * 4 + 2 * d;
        float v0 = aval(m, row, k0,     gw1, gw2, e1w1, e1w2, e2w1, e2w2, tw, sw, hw);
        float v1 = aval(m, row, k0 + 1, gw1, gw2, e1w1, e1w2, e2w1, e2w2, tw, sw, hw);
        ws[t] = pk2(v0, v1);
    } else if (t < 4096) {
        int f = t - 1536;
        int bf = f >> 8, rem = f & 255, lane = rem >> 2, r = rem & 3;
        int row = (lane >> 4) * 4 + r;
        float v = bval(bf, row, gb1, gb2, e1b1, e1b2, e2b1, e2b2, tb, sb, hb);
        ((float*)ws)[t] = v;
    } else if (t < 6144) {
        int f = t - 4096;
        int nf = f >> 8, rem = f & 255, lane = rem >> 2, r = rem & 3;
        int e = nf >> 2, w = nf & 3, g_ = lane >> 4;
        const float* ge = e ? e2g : e1g;
        const float* bne = e ? e2bn : e1bn;
        float v;
        if (w < 2) {
            int feat = g_ * 4 + r;
            v = (w == 0) ? ge[feat] : bne[feat];
        } else {
            int feat = 16 + g_ * 4 + r;
            v = (g_ < 2) ? ((w == 2) ? ge[feat] : bne[feat]) : 0.0f;  // zero at pads AND mu-row
        }
        ((float*)ws)[t] = v;
    }
}

__global__ __launch_bounds__(256) void moe_mfma_kernel(const float* __restrict__ x,
                                                       const u32* __restrict__ ws,
                                                       float* __restrict__ out, int nrows) {
    __shared__ u32 lds[6144];
    for (int i = threadIdx.x; i < 6144; i += 256) lds[i] = ws[i];
    __syncthreads();

    int lane = threadIdx.x & 63;
    int g = lane >> 4, s = lane & 15;
    float mask0 = (g == 2) ? 0.0f : 1.0f;   // exclude mu-row from variance
    int wid = (blockIdx.x * blockDim.x + threadIdx.x) >> 6;
    int nw = (gridDim.x * blockDim.x) >> 6;

    auto LA  = [&](int m)  -> f16x4 { return *(const f16x4*)&lds[m * 128 + lane * 2]; };
    auto LB  = [&](int bf) -> f32x4 { return *(const f32x4*)&lds[1536 + bf * 256 + lane * 4]; };
    auto LNF = [&](int nf) -> f32x4 { return *(const f32x4*)&lds[4096 + nf * 256 + lane * 4]; };

    // Two-tile expert; FIRST folded at inline time.
    auto expert2 = [&](bool FIRST, int mA1a, int mA1b, int mA2a, int mA2b,
                       int bf1a, int bf1b, int bf2, int nf,
                       f16x4 Bx0, f16x4 Bx1, float sc0, float sc1,
                       f32x4& h0, f32x4& h1) {
        f16x4 A1a = LA(mA1a), A1b = LA(mA1b);
        f32x4 b1a = LB(bf1a), b1b = LB(bf1b);
        f32x4 C1_0 = MFMA16(A1a, Bx0, b1a);
        f32x4 C1_1 = MFMA16(A1a, Bx1, b1a);
        f32x4 C2_0 = MFMA16(A1b, Bx0, b1b);
        f32x4 C2_1 = MFMA16(A1b, Bx1, b1b);

        // mu computed by the MFMA mu-row: row 24 -> lane group 2, reg 0
        float mu0 = __shfl(C2_0[0], 32 + s, 64);
        float mu1 = __shfl(C2_1[0], 32 + s, 64);

        float E20 = 0.0f, E21 = 0.0f;
#pragma unroll
        for (int i = 0; i < 4; ++i) {
            E20 = fmaf(C1_0[i], C1_0[i], E20);
            E21 = fmaf(C1_1[i], C1_1[i], E21);
        }
        E20 = fmaf(C2_0[0] * mask0, C2_0[0], E20);
        E21 = fmaf(C2_1[0] * mask0, C2_1[0], E21);
#pragma unroll
        for (int i = 1; i < 4; ++i) {
            E20 = fmaf(C2_0[i], C2_0[i], E20);
            E21 = fmaf(C2_1[i], C2_1[i], E21);
        }
        E20 += __shfl_xor(E20, 16); E20 += __shfl_xor(E20, 32);
        E21 += __shfl_xor(E21, 16); E21 += __shfl_xor(E21, 32);
        float rstd0 = rsqrtf(fmaf(E20, 1.0f / 24.0f, -mu0 * mu0) + LN_EPS);
        float rstd1 = rsqrtf(fmaf(E21, 1.0f / 24.0f, -mu1 * mu1) + LN_EPS);

        f32x4 gc1 = LNF(nf + 0), bc1 = LNF(nf + 1), gc2 = LNF(nf + 2), bc2 = LNF(nf + 3);
        float n0[8], n1[8], sv0[8], sv1[8];
#pragma unroll
        for (int i = 0; i < 4; ++i) {
            n0[i]     = fmaf((C1_0[i] - mu0) * rstd0, gc1[i], bc1[i]);
            n1[i]     = fmaf((C1_1[i] - mu1) * rstd1, gc1[i], bc1[i]);
            n0[4 + i] = fmaf((C2_0[i] - mu0) * rstd0, gc2[i], bc2[i]);
            n1[4 + i] = fmaf((C2_1[i] - mu1) * rstd1, gc2[i], bc2[i]);
        }
        silu_quad(n0[0], n0[1], n0[2], n0[3], sv0[0], sv0[1], sv0[2], sv0[3]);
        silu_quad(n0[4], n0[5], n0[6], n0[7], sv0[4], sv0[5], sv0[6], sv0[7]);
        silu_quad(n1[0], n1[1], n1[2], n1[3], sv1[0], sv1[1], sv1[2], sv1[3]);
        silu_quad(n1[4], n1[5], n1[6], n1[7], sv1[4], sv1[5], sv1[6], sv1[7]);
        f16x4 B1_0 = mk4(sv0[0], sv0[1], sv0[2], sv0[3]);
        f16x4 B2_0 = mk4(sv0[4], sv0[5], sv0[6], sv0[7]);
        f16x4 B1_1 = mk4(sv1[0], sv1[1], sv1[2], sv1[3]);
        f16x4 B2_1 = mk4(sv1[4], sv1[5], sv1[6], sv1[7]);

        f16x4 A2a = LA(mA2a), A2b = LA(mA2b);
        f32x4 b2 = LB(bf2);
        f32x4 O0 = MFMA16(A2a, B1_0, b2);
        f32x4 O1 = MFMA16(A2a, B1_1, b2);
        O0 = MFMA16(A2b, B2_0, O0);
        O1 = MFMA16(A2b, B2_1, O1);

        float p0[4], p1[4];
        silu_quad(O0[0], O0[1], O0[2], O0[3], p0[0], p0[1], p0[2], p0[3]);
        silu_quad(O1[0], O1[1], O1[2], O1[3], p1[0], p1[1], p1[2], p1[3]);
#pragma unroll
        for (int i = 0; i < 4; ++i) {
            if (FIRST) {
                h0[i] = sc0 * p0[i];
                h1[i] = sc1 * p1[i];
            } else {
                h0[i] = fmaf(sc0, p0[i], h0[i]);
                h1[i] = fmaf(sc1, p1[i], h1[i]);
            }
        }
    };

    int ntiles = (nrows + 15) >> 4;
    int nclamp = nrows - 1;

    auto loadx = [&](int tile) -> f32x4 {
        int r = tile * 16 + s;
        int rc = r < nrows ? r : nclamp;
        return *(const f32x4*)(x + (size_t)rc * 16 + g * 4);
    };

    int p0 = 2 * wid;
    f32x4 xv0, xv1;
    if (p0 < ntiles) {
        xv0 = loadx(p0);
        xv1 = loadx(p0 + 1 < ntiles ? p0 + 1 : p0);
    }

    for (int tp = p0; tp < ntiles; tp += 2 * nw) {
        int tnp = tp + 2 * nw;
        f32x4 xn0, xn1;
        {
            int t0n = tnp < ntiles ? tnp : tp;
            int t1n = tnp + 1 < ntiles ? tnp + 1 : t0n;
            xn0 = loadx(t0n);
            xn1 = loadx(t1n);
        }

        int r0 = tp * 16 + s;
        int r1 = (tp + 1) * 16 + s;
        f16x4 Bx0 = mk4(xv0[0], xv0[1], xv0[2], xv0[3]);
        f16x4 Bx1 = mk4(xv1[0], xv1[1], xv1[2], xv1[3]);

        // ---- gate ----
        f32x4 Cg0 = MFMA16(LA(0), Bx0, LB(0));
        f32x4 Cg1 = MFMA16(LA(0), Bx1, LB(0));
        float a0, a1, a2, a3, b0, b1, b2_, b3;
        tanh_quad(Cg0[0], Cg0[1], Cg0[2], Cg0[3], a0, a1, a2, a3);
        tanh_quad(Cg1[0], Cg1[1], Cg1[2], Cg1[3], b0, b1, b2_, b3);
        f16x4 Bt0 = mk4(a0, a1, a2, a3);
        f16x4 Bt1 = mk4(b0, b1, b2_, b3);
        f32x4 Cl0 = MFMA16(LA(1), Bt0, LB(1));
        f32x4 Cl1 = MFMA16(LA(1), Bt1, LB(1));
        float w00 = fast_rcp(1.0f + __expf(Cl0[1] - Cl0[0]));
        float w01 = 1.0f - w00;
        float w10 = fast_rcp(1.0f + __expf(Cl1[1] - Cl1[0]));
        float w11 = 1.0f - w10;

        // ---- experts ----
        f32x4 h0, h1;
        expert2(true,  2, 3, 4, 5, 2, 3, 4, 0, Bx0, Bx1, w00, w10, h0, h1);
        expert2(false, 6, 7, 8, 9, 5, 6, 7, 4, Bx0, Bx1, w01, w11, h0, h1);

        // ---- trunk ----
        f16x4 Bh0 = mk4(h0[0], h0[1], h0[2], h0[3]);
        f16x4 Bh1 = mk4(h1[0], h1[1], h1[2], h1[3]);
        f32x4 Ct0 = MFMA16(LA(10), Bh0, LB(8));
        f32x4 Ct1 = MFMA16(LA(10), Bh1, LB(8));
        float u0[4], u1[4];
        silu_quad(Ct0[0], Ct0[1], Ct0[2], Ct0[3], u0[0], u0[1], u0[2], u0[3]);
        silu_quad(Ct1[0], Ct1[1], Ct1[2], Ct1[3], u1[0], u1[1], u1[2], u1[3]);
        f16x4 Bu0 = mk4(u0[0], u0[1], u0[2], u0[3]);
        f16x4 Bu1 = mk4(u1[0], u1[1], u1[2], u1[3]);

        // ---- heads ----
        f32x4 Ch0 = MFMA16(LA(11), Bu0, LB(9));
        f32x4 Ch1 = MFMA16(LA(11), Bu1, LB(9));
        if (g == 0) {
            if (r0 < nrows) {
                float yld = Ch0[1] - softplus_f(Ch0[2]);
                size_t o = (size_t)r0 * 3;
                out[o + 0] = Ch0[0];
                out[o + 1] = Ch0[1];
                out[o + 2] = yld;
            }
            if (r1 < nrows) {
                float yld = Ch1[1] - softplus_f(Ch1[2]);
                size_t o = (size_t)r1 * 3;
                out[o + 0] = Ch1[0];
                out[o + 1] = Ch1[1];
                out[o + 2] = yld;
            }
        }

        xv0 = xn0;
        xv1 = xn1;
    }
}

extern "C" void kernel_launch(void* const* d_in, const int* in_sizes, int n_in,
                              void* d_out, int out_size, void* d_ws, size_t ws_size,
                              hipStream_t stream) {
    const float* x    = (const float*)d_in[0];
    const float* gw1  = (const float*)d_in[1];
    const float* gb1  = (const float*)d_in[2];
    const float* gw2  = (const float*)d_in[3];
    const float* gb2  = (const float*)d_in[4];
    const float* e1w1 = (const float*)d_in[5];
    const float* e1b1 = (const float*)d_in[6];
    const float* e1g  = (const float*)d_in[7];
    const float* e1bn = (const float*)d_in[8];
    const float* e1w2 = (const float*)d_in[9];
    const float* e1b2 = (const float*)d_in[10];
    const float* e2w1 = (const float*)d_in[11];
    const float* e2b1 = (const float*)d_in[12];
    const float* e2g  = (const float*)d_in[13];
    const float* e2bn = (const float*)d_in[14];
    const float* e2w2 = (const float*)d_in[15];
    const float* e2b2 = (const float*)d_in[16];
    const float* tw   = (const float*)d_in[17];
    const float* tb   = (const float*)d_in[18];
    const float* sw   = (const float*)d_in[19];
    const float* sb   = (const float*)d_in[20];
    const float* hw   = (const float*)d_in[21];
    const float* hb   = (const float*)d_in[22];
    float* out = (float*)d_out;
    u32* ws = (u32*)d_ws;

    pack_frags<<<24, 256, 0, stream>>>(gw1, gb1, gw2, gb2,
                                       e1w1, e1b1, e1g, e1bn, e1w2, e1b2,
                                       e2w1, e2b1, e2g, e2bn, e2w2, e2b2,
                                       tw, tb, sw, sb, hw, hb, ws);

    int nrows = in_sizes[0] / 16;
    moe_mfma_kernel<<<2048, 256, 0, stream>>>(x, ws, out, nrows);
}

// Round 14
// 101.621 us; speedup vs baseline: 1.2195x; 1.1863x over previous
//
#include <hip/hip_runtime.h>

#define LN_EPS 1e-5f

typedef _Float16 f16x4 __attribute__((ext_vector_type(4)));
typedef float f32x4 __attribute__((ext_vector_type(4)));
typedef unsigned int u32;
typedef u32 u32x2 __attribute__((ext_vector_type(2)));

#if defined(__HIP_DEVICE_COMPILE__)
#  if __has_builtin(__builtin_amdgcn_mfma_f32_16x16x16f16)
#    define MFMA16(a, b, c) __builtin_amdgcn_mfma_f32_16x16x16f16(a, b, c, 0, 0, 0)
#  elif __has_builtin(__builtin_amdgcn_mfma_f32_16x16x16_f16)
#    define MFMA16(a, b, c) __builtin_amdgcn_mfma_f32_16x16x16_f16(a, b, c, 0, 0, 0)
#  else
#    error "no 16x16x16 f16 mfma builtin on device"
#  endif
#else
#  define MFMA16(a, b, c) (c)   /* host pass: parse-only dummy, never executed */
#endif

__device__ __forceinline__ float fast_rcp(float x) { return __builtin_amdgcn_rcpf(x); }

__device__ __forceinline__ u32 pk2(float a, float b) {
    return __builtin_bit_cast(u32, __builtin_amdgcn_cvt_pkrtz(a, b));
}
__device__ __forceinline__ f16x4 mk4(float a, float b, float c, float d) {
    u32x2 t = {pk2(a, b), pk2(c, d)};
    return __builtin_bit_cast(f16x4, t);
}

// Unclamped per-element silu: overflow self-corrects (exp->inf -> rcp->0 -> 0, exact limit).
__device__ __forceinline__ float silu_f(float a) {
    return a * fast_rcp(1.0f + __expf(-a));
}
// Unclamped per-element tanh: 2/(1+exp(-2x)) - 1; exp->inf -> rcp->0 -> -1, exact limit.
__device__ __forceinline__ float tanh_f(float x) {
    return fmaf(2.0f, fast_rcp(1.0f + __expf(-2.0f * x)), -1.0f);
}
__device__ __forceinline__ float softplus_f(float x) {
    float e = __expf(-fabsf(x));
    return fmaxf(x, 0.0f) + __logf(1.0f + e);
}

// ======================= d_ws layout (dword units) =======================
// [0, 1536):   A fragments, 12 mfma x 64 lanes x 2 dwords (f16x4 each)
//              0:g1 1:g2(logits replicated) 2:e1L1a 3:e1L1b(+murow@8) 4:e1L2a 5:e1L2b
//              6:e2L1a 7:e2L1b(+murow@8) 8:e2L2a 9:e2L2b 10:trunk 11:heads
// [1536,4096): bias C-in fragments, 10 x 64 x 4 f32 (L1b rows get mean-bias@8)
// [4096,6144): LN norm fragments, (expert*4+w) x 64 x 4 f32
// =========================================================================

__device__ __forceinline__ float aval(int m, int row, int k,
                                      const float* gw1, const float* gw2,
                                      const float* e1w1, const float* e1w2,
                                      const float* e2w1, const float* e2w2,
                                      const float* tw, const float* sw, const float* hw) {
    switch (m) {
        case 0:  return (row < 8) ? gw1[k * 8 + row] : 0.0f;
        case 1:  return ((row & 3) < 2 && k < 8) ? gw2[k * 2 + (row & 3)] : 0.0f;
        case 2:  return e1w1[k * 24 + row];
        case 3: {
            if (row < 8) return e1w1[k * 24 + 16 + row];
            if (row == 8) {
                float t = 0.0f;
                for (int j = 0; j < 24; ++j) t += e1w1[k * 24 + j];
                return t * (1.0f / 24.0f);
            }
            return 0.0f;
        }
        case 4:  return e1w2[k * 16 + row];
        case 5:  return (k < 8) ? e1w2[(16 + k) * 16 + row] : 0.0f;
        case 6:  return e2w1[k * 24 + row];
        case 7: {
            if (row < 8) return e2w1[k * 24 + 16 + row];
            if (row == 8) {
                float t = 0.0f;
                for (int j = 0; j < 24; ++j) t += e2w1[k * 24 + j];
                return t * (1.0f / 24.0f);
            }
            return 0.0f;
        }
        case 8:  return e2w2[k * 16 + row];
        case 9:  return (k < 8) ? e2w2[(16 + k) * 16 + row] : 0.0f;
        case 10: return tw[k * 16 + row];
        default:
            if (row == 0) return sw[k];
            if (row == 1) return hw[2 * k + 0];
            if (row == 2) return hw[2 * k + 1];
            return 0.0f;
    }
}

__device__ __forceinline__ float bval(int bf, int row,
                                      const float* gb1, const float* gb2,
                                      const float* e1b1, const float* e1b2,
                                      const float* e2b1, const float* e2b2,
                                      const float* tb, const float* sb, const float* hb) {
    switch (bf) {
        case 0:  return (row < 8) ? gb1[row] : 0.0f;
        case 1:  return ((row & 3) < 2) ? gb2[row & 3] : 0.0f;
        case 2:  return e1b1[row];
        case 3: {
            if (row < 8) return e1b1[16 + row];
            if (row == 8) {
                float t = 0.0f;
                for (int j = 0; j < 24; ++j) t += e1b1[j];
                return t * (1.0f / 24.0f);
            }
            return 0.0f;
        }
        case 4:  return e1b2[row];
        case 5:  return e2b1[row];
        case 6: {
            if (row < 8) return e2b1[16 + row];
            if (row == 8) {
                float t = 0.0f;
                for (int j = 0; j < 24; ++j) t += e2b1[j];
                return t * (1.0f / 24.0f);
            }
            return 0.0f;
        }
        case 7:  return e2b2[row];
        case 8:  return tb[row];
        default:
            if (row == 0) return sb[0];
            if (row == 1) return hb[0];
            if (row == 2) return hb[1];
            return 0.0f;
    }
}

__global__ void pack_frags(const float* __restrict__ gw1, const float* __restrict__ gb1,
                           const float* __restrict__ gw2, const float* __restrict__ gb2,
                           const float* __restrict__ e1w1, const float* __restrict__ e1b1,
                           const float* __restrict__ e1g, const float* __restrict__ e1bn,
                           const float* __restrict__ e1w2, const float* __restrict__ e1b2,
                           const float* __restrict__ e2w1, const float* __restrict__ e2b1,
                           const float* __restrict__ e2g, const float* __restrict__ e2bn,
                           const float* __restrict__ e2w2, const float* __restrict__ e2b2,
                           const float* __restrict__ tw, const float* __restrict__ tb,
                           const float* __restrict__ sw, const float* __restrict__ sb,
                           const float* __restrict__ hw, const float* __restrict__ hb,
                           u32* __restrict__ ws) {
    int t = blockIdx.x * blockDim.x + threadIdx.x;
    if (t < 1536) {
        int m = t >> 7, rem = t & 127, lane = rem >> 1, d = rem & 1;
        int row = lane & 15, k0 = (lane >> 4) * 4 + 2 * d;
        float v0 = aval(m, row, k0,     gw1, gw2, e1w1, e1w2, e2w1, e2w2, tw, sw, hw);
        float v1 = aval(m, row, k0 + 1, gw1, gw2, e1w1, e1w2, e2w1, e2w2, tw, sw, hw);
        ws[t] = pk2(v0, v1);
    } else if (t < 4096) {
        int f = t - 1536;
        int bf = f >> 8, rem = f & 255, lane = rem >> 2, r = rem & 3;
        int row = (lane >> 4) * 4 + r;
        float v = bval(bf, row, gb1, gb2, e1b1, e1b2, e2b1, e2b2, tb, sb, hb);
        ((float*)ws)[t] = v;
    } else if (t < 6144) {
        int f = t - 4096;
        int nf = f >> 8, rem = f & 255, lane = rem >> 2, r = rem & 3;
        int e = nf >> 2, w = nf & 3, g_ = lane >> 4;
        const float* ge = e ? e2g : e1g;
        const float* bne = e ? e2bn : e1bn;
        float v;
        if (w < 2) {
            int feat = g_ * 4 + r;
            v = (w == 0) ? ge[feat] : bne[feat];
        } else {
            int feat = 16 + g_ * 4 + r;
            v = (g_ < 2) ? ((w == 2) ? ge[feat] : bne[feat]) : 0.0f;
        }
        ((float*)ws)[t] = v;
    }
}

__global__ __launch_bounds__(256) void moe_mfma_kernel(const float* __restrict__ x,
                                                       const u32* __restrict__ ws,
                                                       float* __restrict__ out, int nrows) {
    __shared__ u32 lds[6144];
    for (int i = threadIdx.x; i < 6144; i += 256) lds[i] = ws[i];
    __syncthreads();

    int lane = threadIdx.x & 63;
    int g = lane >> 4, s = lane & 15;
    float mask0 = (g == 2) ? 0.0f : 1.0f;   // exclude mu-row from variance
    int wid = (blockIdx.x * blockDim.x + threadIdx.x) >> 6;
    int nw = (gridDim.x * blockDim.x) >> 6;

    auto LA  = [&](int m)  -> f16x4 { return *(const f16x4*)&lds[m * 128 + lane * 2]; };
    auto LB  = [&](int bf) -> f32x4 { return *(const f32x4*)&lds[1536 + bf * 256 + lane * 4]; };
    auto LNF = [&](int nf) -> f32x4 { return *(const f32x4*)&lds[4096 + nf * 256 + lane * 4]; };

    auto expert2 = [&](bool FIRST, int mA1a, int mA1b, int mA2a, int mA2b,
                       int bf1a, int bf1b, int bf2, int nf,
                       f16x4 Bx0, f16x4 Bx1, float sc0, float sc1,
                       f32x4& h0, f32x4& h1) {
        f16x4 A1a = LA(mA1a), A1b = LA(mA1b);
        f32x4 b1a = LB(bf1a), b1b = LB(bf1b);
        f32x4 C1_0 = MFMA16(A1a, Bx0, b1a);
        f32x4 C1_1 = MFMA16(A1a, Bx1, b1a);
        f32x4 C2_0 = MFMA16(A1b, Bx0, b1b);
        f32x4 C2_1 = MFMA16(A1b, Bx1, b1b);

        float mu0 = __shfl(C2_0[0], 32 + s, 64);
        float mu1 = __shfl(C2_1[0], 32 + s, 64);

        float E20 = 0.0f, E21 = 0.0f;
#pragma unroll
        for (int i = 0; i < 4; ++i) {
            E20 = fmaf(C1_0[i], C1_0[i], E20);
            E21 = fmaf(C1_1[i], C1_1[i], E21);
        }
        E20 = fmaf(C2_0[0] * mask0, C2_0[0], E20);
        E21 = fmaf(C2_1[0] * mask0, C2_1[0], E21);
#pragma unroll
        for (int i = 1; i < 4; ++i) {
            E20 = fmaf(C2_0[i], C2_0[i], E20);
            E21 = fmaf(C2_1[i], C2_1[i], E21);
        }
        E20 += __shfl_xor(E20, 16); E20 += __shfl_xor(E20, 32);
        E21 += __shfl_xor(E21, 16); E21 += __shfl_xor(E21, 32);
        float rstd0 = rsqrtf(fmaf(E20, 1.0f / 24.0f, -mu0 * mu0) + LN_EPS);
        float rstd1 = rsqrtf(fmaf(E21, 1.0f / 24.0f, -mu1 * mu1) + LN_EPS);

        f32x4 gc1 = LNF(nf + 0), bc1 = LNF(nf + 1), gc2 = LNF(nf + 2), bc2 = LNF(nf + 3);
        float sv0[8], sv1[8];
#pragma unroll
        for (int i = 0; i < 4; ++i) {
            sv0[i]     = silu_f(fmaf((C1_0[i] - mu0) * rstd0, gc1[i], bc1[i]));
            sv1[i]     = silu_f(fmaf((C1_1[i] - mu1) * rstd1, gc1[i], bc1[i]));
            sv0[4 + i] = silu_f(fmaf((C2_0[i] - mu0) * rstd0, gc2[i], bc2[i]));
            sv1[4 + i] = silu_f(fmaf((C2_1[i] - mu1) * rstd1, gc2[i], bc2[i]));
        }
        f16x4 B1_0 = mk4(sv0[0], sv0[1], sv0[2], sv0[3]);
        f16x4 B2_0 = mk4(sv0[4], sv0[5], sv0[6], sv0[7]);
        f16x4 B1_1 = mk4(sv1[0], sv1[1], sv1[2], sv1[3]);
        f16x4 B2_1 = mk4(sv1[4], sv1[5], sv1[6], sv1[7]);

        f16x4 A2a = LA(mA2a), A2b = LA(mA2b);
        f32x4 b2 = LB(bf2);
        f32x4 O0 = MFMA16(A2a, B1_0, b2);
        f32x4 O1 = MFMA16(A2a, B1_1, b2);
        O0 = MFMA16(A2b, B2_0, O0);
        O1 = MFMA16(A2b, B2_1, O1);

#pragma unroll
        for (int i = 0; i < 4; ++i) {
            float p0 = silu_f(O0[i]);
            float p1 = silu_f(O1[i]);
            if (FIRST) {
                h0[i] = sc0 * p0;
                h1[i] = sc1 * p1;
            } else {
                h0[i] = fmaf(sc0, p0, h0[i]);
                h1[i] = fmaf(sc1, p1, h1[i]);
            }
        }
    };

    int ntiles = (nrows + 15) >> 4;
    int nclamp = nrows - 1;

    auto loadx = [&](int tile) -> f32x4 {
        int r = tile * 16 + s;
        int rc = r < nrows ? r : nclamp;
        return *(const f32x4*)(x + (size_t)rc * 16 + g * 4);
    };

    int p0 = 2 * wid;
    f32x4 xv0, xv1;
    if (p0 < ntiles) {
        xv0 = loadx(p0);
        xv1 = loadx(p0 + 1 < ntiles ? p0 + 1 : p0);
    }

    for (int tp = p0; tp < ntiles; tp += 2 * nw) {
        int tnp = tp + 2 * nw;
        f32x4 xn0, xn1;
        {
            int t0n = tnp < ntiles ? tnp : tp;
            int t1n = tnp + 1 < ntiles ? tnp + 1 : t0n;
            xn0 = loadx(t0n);
            xn1 = loadx(t1n);
        }

        int r0 = tp * 16 + s;
        int r1 = (tp + 1) * 16 + s;
        f16x4 Bx0 = mk4(xv0[0], xv0[1], xv0[2], xv0[3]);
        f16x4 Bx1 = mk4(xv1[0], xv1[1], xv1[2], xv1[3]);

        // ---- gate ----
        f32x4 Cg0 = MFMA16(LA(0), Bx0, LB(0));
        f32x4 Cg1 = MFMA16(LA(0), Bx1, LB(0));
        f16x4 Bt0 = mk4(tanh_f(Cg0[0]), tanh_f(Cg0[1]), tanh_f(Cg0[2]), tanh_f(Cg0[3]));
        f16x4 Bt1 = mk4(tanh_f(Cg1[0]), tanh_f(Cg1[1]), tanh_f(Cg1[2]), tanh_f(Cg1[3]));
        f32x4 Cl0 = MFMA16(LA(1), Bt0, LB(1));
        f32x4 Cl1 = MFMA16(LA(1), Bt1, LB(1));
        float w00 = fast_rcp(1.0f + __expf(Cl0[1] - Cl0[0]));
        float w01 = 1.0f - w00;
        float w10 = fast_rcp(1.0f + __expf(Cl1[1] - Cl1[0]));
        float w11 = 1.0f - w10;

        // ---- experts ----
        f32x4 h0, h1;
        expert2(true,  2, 3, 4, 5, 2, 3, 4, 0, Bx0, Bx1, w00, w10, h0, h1);
        expert2(false, 6, 7, 8, 9, 5, 6, 7, 4, Bx0, Bx1, w01, w11, h0, h1);

        // ---- trunk ----
        f16x4 Bh0 = mk4(h0[0], h0[1], h0[2], h0[3]);
        f16x4 Bh1 = mk4(h1[0], h1[1], h1[2], h1[3]);
        f32x4 Ct0 = MFMA16(LA(10), Bh0, LB(8));
        f32x4 Ct1 = MFMA16(LA(10), Bh1, LB(8));
        f16x4 Bu0 = mk4(silu_f(Ct0[0]), silu_f(Ct0[1]), silu_f(Ct0[2]), silu_f(Ct0[3]));
        f16x4 Bu1 = mk4(silu_f(Ct1[0]), silu_f(Ct1[1]), silu_f(Ct1[2]), silu_f(Ct1[3]));

        // ---- heads ----
        f32x4 Ch0 = MFMA16(LA(11), Bu0, LB(9));
        f32x4 Ch1 = MFMA16(LA(11), Bu1, LB(9));
        if (g == 0) {
            if (r0 < nrows) {
                float yld = Ch0[1] - softplus_f(Ch0[2]);
                size_t o = (size_t)r0 * 3;
                out[o + 0] = Ch0[0];
                out[o + 1] = Ch0[1];
                out[o + 2] = yld;
            }
            if (r1 < nrows) {
                float yld = Ch1[1] - softplus_f(Ch1[2]);
                size_t o = (size_t)r1 * 3;
                out[o + 0] = Ch1[0];
                out[o + 1] = Ch1[1];
                out[o + 2] = yld;
            }
        }

        xv0 = xn0;
        xv1 = xn1;
    }
}

extern "C" void kernel_launch(void* const* d_in, const int* in_sizes, int n_in,
                              void* d_out, int out_size, void* d_ws, size_t ws_size,
                              hipStream_t stream) {
    const float* x    = (const float*)d_in[0];
    const float* gw1  = (const float*)d_in[1];
    const float* gb1  = (const float*)d_in[2];
    const float* gw2  = (const float*)d_in[3];
    const float* gb2  = (const float*)d_in[4];
    const float* e1w1 = (const float*)d_in[5];
    const float* e1b1 = (const float*)d_in[6];
    const float* e1g  = (const float*)d_in[7];
    const float* e1bn = (const float*)d_in[8];
    const float* e1w2 = (const float*)d_in[9];
    const float* e1b2 = (const float*)d_in[10];
    const float* e2w1 = (const float*)d_in[11];
    const float* e2b1 = (const float*)d_in[12];
    const float* e2g  = (const float*)d_in[13];
    const float* e2bn = (const float*)d_in[14];
    const float* e2w2 = (const float*)d_in[15];
    const float* e2b2 = (const float*)d_in[16];
    const float* tw   = (const float*)d_in[17];
    const float* tb   = (const float*)d_in[18];
    const float* sw   = (const float*)d_in[19];
    const float* sb   = (const float*)d_in[20];
    const float* hw   = (const float*)d_in[21];
    const float* hb   = (const float*)d_in[22];
    float* out = (float*)d_out;
    u32* ws = (u32*)d_ws;

    pack_frags<<<24, 256, 0, stream>>>(gw1, gb1, gw2, gb2,
                                       e1w1, e1b1, e1g, e1bn, e1w2, e1b2,
                                       e2w1, e2b1, e2g, e2bn, e2w2, e2b2,
                                       tw, tb, sw, sb, hw, hb, ws);

    int nrows = in_sizes[0] / 16;
    moe_mfma_kernel<<<2048, 256, 0, stream>>>(x, ws, out, nrows);
}